// Round 1
// baseline (134.012 us; speedup 1.0000x reference)
//
#include <hip/hip_runtime.h>

// GAT layer, N=8192, IN_F=512, OUT_F=64, alpha=0.2
// Key identity: leaky_relu is piecewise linear =>
//   exp(lrelu(s1_i+s2_j)) = exp(s1_i)*exp(s2_j)            if s1_i+s2_j > 0
//                         = exp(.2*s1_i)*exp(.2*s2_j)      otherwise
// Partition j by s2_j <= -s1_i  => prefix/suffix sums over rank-sorted s2.
// Total work O(N*F) instead of O(N^2*F). adj input is unused by the reference.

constexpr int NV   = 8192;
constexpr int FIN  = 512;
constexpr int FOUT = 64;
constexpr int NCH  = 128;   // NV / 64 chunks of 64 sorted positions

// ---------------------------------------------------------------- K0
// Transpose W[64][512] -> Wtt tiled so a wave's 64 lanes read 1KB contiguous:
// Wtt[(k>>2)*256 + f*4 + (k&3)] = W[f][k]
__global__ __launch_bounds__(256) void k0_transpose(const float* __restrict__ W,
                                                    float* __restrict__ Wtt) {
    int id = blockIdx.x * 256 + threadIdx.x;      // 0..32767
    int f = id >> 9;
    int k = id & 511;
    Wtt[(k >> 2) * 256 + f * 4 + (k & 3)] = W[id];
}

// ---------------------------------------------------------------- K1
// Wh = h @ W^T ; s1 = Wh@a1 ; s2 = Wh@a2
// block 256 = 4 waves; each wave owns 8 rows (lane = output feature f).
__global__ __launch_bounds__(256) void k1_wh(const float* __restrict__ h,
                                             const float* __restrict__ Wtt,
                                             const float* __restrict__ a,
                                             float* __restrict__ Wh,
                                             float* __restrict__ s1,
                                             float* __restrict__ s2) {
    const int wave = threadIdx.x >> 6;
    const int lane = threadIdx.x & 63;
    const int r0 = (blockIdx.x * 4 + wave) * 8;
    float acc[8] = {0.f,0.f,0.f,0.f,0.f,0.f,0.f,0.f};
    const float* hbase = h + (size_t)r0 * FIN;
    for (int k4 = 0; k4 < FIN / 4; ++k4) {
        const float4 wv = *reinterpret_cast<const float4*>(Wtt + k4 * 256 + lane * 4);
        #pragma unroll
        for (int r = 0; r < 8; ++r) {
            const float4 hv = *reinterpret_cast<const float4*>(hbase + (size_t)r * FIN + k4 * 4);
            acc[r] = fmaf(hv.x, wv.x, acc[r]);
            acc[r] = fmaf(hv.y, wv.y, acc[r]);
            acc[r] = fmaf(hv.z, wv.z, acc[r]);
            acc[r] = fmaf(hv.w, wv.w, acc[r]);
        }
    }
    const float a1 = a[lane];
    const float a2 = a[FOUT + lane];
    #pragma unroll
    for (int r = 0; r < 8; ++r) {
        Wh[(size_t)(r0 + r) * FOUT + lane] = acc[r];
        float p1 = acc[r] * a1;
        float p2 = acc[r] * a2;
        #pragma unroll
        for (int off = 32; off > 0; off >>= 1) {
            p1 += __shfl_xor(p1, off);
            p2 += __shfl_xor(p2, off);
        }
        if (lane == 0) { s1[r0 + r] = p1; s2[r0 + r] = p2; }
    }
}

// ---------------------------------------------------------------- K2
// blocks [0,256): rank each j by (s2_j, j) and scatter exp(s2)/exp(.2*s2)
// blocks [256,512): k_i = #{ j : s2_j <= -s1_i } per row i
// Each id gets 8 threads (segments of 1024), reduced via shfl.
__global__ __launch_bounds__(256) void k2_rank(const float* __restrict__ s1,
                                               const float* __restrict__ s2,
                                               int*   __restrict__ sortedIdx,
                                               float* __restrict__ sortedU,
                                               float* __restrict__ sortedV,
                                               int*   __restrict__ kcut) {
    __shared__ float s2s[NV];
    for (int q = 0; q < NV / 256; ++q)
        s2s[q * 256 + threadIdx.x] = s2[q * 256 + threadIdx.x];
    __syncthreads();
    const bool doRank = blockIdx.x < 256;
    const int bid = blockIdx.x & 255;
    const int idl = threadIdx.x >> 3;      // 0..31
    const int seg = threadIdx.x & 7;       // 0..7
    const int id  = bid * 32 + idl;        // 0..8191
    const float key = doRank ? s2s[id] : -s1[id];
    int cnt = 0;
    const int base = seg * 1024;
    if (doRank) {
        for (int kk = 0; kk < 256; ++kk) {
            const float4 v = *reinterpret_cast<const float4*>(&s2s[base + kk * 4]);
            const int gj = base + kk * 4;
            cnt += (v.x < key) || (v.x == key && (gj + 0) < id);
            cnt += (v.y < key) || (v.y == key && (gj + 1) < id);
            cnt += (v.z < key) || (v.z == key && (gj + 2) < id);
            cnt += (v.w < key) || (v.w == key && (gj + 3) < id);
        }
    } else {
        for (int kk = 0; kk < 256; ++kk) {
            const float4 v = *reinterpret_cast<const float4*>(&s2s[base + kk * 4]);
            cnt += (int)(v.x <= key) + (int)(v.y <= key)
                 + (int)(v.z <= key) + (int)(v.w <= key);
        }
    }
    cnt += __shfl_xor(cnt, 1);
    cnt += __shfl_xor(cnt, 2);
    cnt += __shfl_xor(cnt, 4);
    if (seg == 0) {
        if (doRank) {
            sortedIdx[cnt] = id;
            sortedU[cnt] = __expf(key);
            sortedV[cnt] = __expf(0.2f * key);
        } else {
            kcut[id] = cnt;
        }
    }
}

// ---------------------------------------------------------------- K4
// Per 64-position chunk c: vector sums of u*Wh and v*Wh (+ scalar sums).
__global__ __launch_bounds__(64) void k4_chunks(const float* __restrict__ Wh,
                                                const int*   __restrict__ sortedIdx,
                                                const float* __restrict__ sortedU,
                                                const float* __restrict__ sortedV,
                                                float* __restrict__ chunkU,
                                                float* __restrict__ chunkV,
                                                float* __restrict__ suc,
                                                float* __restrict__ svc) {
    const int c = blockIdx.x;
    const int f = threadIdx.x;
    float au = 0.f, av = 0.f, su = 0.f, sv = 0.f;
    for (int q = 0; q < 64; ++q) {
        const int p = c * 64 + q;
        const int j = sortedIdx[p];
        const float u = sortedU[p];
        const float v = sortedV[p];
        const float w = Wh[(size_t)j * FOUT + f];
        au = fmaf(u, w, au);
        av = fmaf(v, w, av);
        su += u; sv += v;
    }
    chunkU[c * FOUT + f] = au;
    chunkV[c * FOUT + f] = av;
    if (f == 0) { suc[c] = su; svc[c] = sv; }
}

// ---------------------------------------------------------------- K5
// Suffix sums for U (no cancellation), exclusive prefix sums for V. 1 block.
__global__ __launch_bounds__(192) void k5_scan(const float* __restrict__ chunkU,
                                               const float* __restrict__ chunkV,
                                               const float* __restrict__ suc,
                                               const float* __restrict__ svc,
                                               float* __restrict__ Usuf,    // [130][64]
                                               float* __restrict__ Vpref,   // [129][64]
                                               float* __restrict__ susuf,   // [130]
                                               float* __restrict__ svpref)  // [129]
{
    const int t = threadIdx.x;
    if (t < 64) {
        float run = 0.f;
        Usuf[129 * FOUT + t] = 0.f;
        Usuf[128 * FOUT + t] = 0.f;
        for (int c = NCH - 1; c >= 0; --c) {
            run += chunkU[c * FOUT + t];
            Usuf[c * FOUT + t] = run;
        }
    } else if (t < 128) {
        const int f = t - 64;
        float run = 0.f;
        for (int c = 0; c < NCH; ++c) {
            Vpref[c * FOUT + f] = run;
            run += chunkV[c * FOUT + f];
        }
        Vpref[NCH * FOUT + f] = run;
    } else if (t == 128) {
        float run = 0.f;
        susuf[129] = 0.f; susuf[128] = 0.f;
        for (int c = NCH - 1; c >= 0; --c) { run += suc[c]; susuf[c] = run; }
    } else if (t == 129) {
        float run = 0.f;
        for (int c = 0; c < NCH; ++c) { svpref[c] = run; run += svc[c]; }
        svpref[NCH] = run;
    }
}

// ---------------------------------------------------------------- K6
// Per row i: combine chunk prefix/suffix + partial chunk (<=64 gathers).
__global__ __launch_bounds__(256) void k6_out(const float* __restrict__ Wh,
                                              const float* __restrict__ s1,
                                              const int*   __restrict__ sortedIdx,
                                              const float* __restrict__ sortedU,
                                              const float* __restrict__ sortedV,
                                              const int*   __restrict__ kcut,
                                              const float* __restrict__ Usuf,
                                              const float* __restrict__ Vpref,
                                              const float* __restrict__ susuf,
                                              const float* __restrict__ svpref,
                                              float* __restrict__ out) {
    const int wave = threadIdx.x >> 6;
    const int f = threadIdx.x & 63;
    const int i = blockIdx.x * 4 + wave;
    const int k = kcut[i];
    const int c = k >> 6;                 // 0..128
    float accU = 0.f, accV = 0.f, sau = 0.f, sav = 0.f;
    const int pstart = c * 64;
    const int pend = min(pstart + 64, NV);
    for (int p = pstart; p < pend; ++p) {
        const int j = sortedIdx[p];
        const float w = Wh[(size_t)j * FOUT + f];
        if (p < k) {                      // wave-uniform branch
            const float v = sortedV[p];
            accV = fmaf(v, w, accV);
            sav += v;
        } else {
            const float u = sortedU[p];
            accU = fmaf(u, w, accU);
            sau += u;
        }
    }
    const int cn = c + 1;                 // <=129
    const float sv1 = s1[i];
    const float A = __expf(sv1);
    const float B = __expf(0.2f * sv1);
    const float numer = A * (Usuf[cn * FOUT + f] + accU) + B * (Vpref[c * FOUT + f] + accV);
    const float den   = A * (susuf[cn] + sau)            + B * (svpref[c] + sav);
    out[(size_t)i * FOUT + f] = numer / den;
}

// ----------------------------------------------------------------
extern "C" void kernel_launch(void* const* d_in, const int* in_sizes, int n_in,
                              void* d_out, int out_size, void* d_ws, size_t ws_size,
                              hipStream_t stream) {
    (void)in_sizes; (void)n_in; (void)out_size; (void)ws_size;
    const float* h = (const float*)d_in[0];
    // d_in[1] = adj : unused by the reference computation
    const float* W = (const float*)d_in[2];
    const float* a = (const float*)d_in[3];
    float* out = (float*)d_out;

    // workspace layout: ints first, then floats (all 16B-aligned enough)
    int* sortedIdx = (int*)d_ws;                    // 8192
    int* kcut      = sortedIdx + NV;                // 8192
    float* fws = (float*)d_ws + 2 * NV;             // floats start at +64KB
    float* Wtt     = fws;            fws += 32768;  // 512*64
    float* Wh      = fws;            fws += (size_t)NV * FOUT;
    float* s1      = fws;            fws += NV;
    float* s2      = fws;            fws += NV;
    float* sortedU = fws;            fws += NV;
    float* sortedV = fws;            fws += NV;
    float* chunkU  = fws;            fws += NCH * FOUT;
    float* chunkV  = fws;            fws += NCH * FOUT;
    float* suc     = fws;            fws += NCH;
    float* svc     = fws;            fws += NCH;
    float* Usuf    = fws;            fws += 130 * FOUT;
    float* Vpref   = fws;            fws += 129 * FOUT;
    float* susuf   = fws;            fws += 130;
    float* svpref  = fws;            fws += 129;

    hipLaunchKernelGGL(k0_transpose, dim3(128), dim3(256), 0, stream, W, Wtt);
    hipLaunchKernelGGL(k1_wh,        dim3(256), dim3(256), 0, stream, h, Wtt, a, Wh, s1, s2);
    hipLaunchKernelGGL(k2_rank,      dim3(512), dim3(256), 0, stream,
                       s1, s2, sortedIdx, sortedU, sortedV, kcut);
    hipLaunchKernelGGL(k4_chunks,    dim3(NCH), dim3(64), 0, stream,
                       Wh, sortedIdx, sortedU, sortedV, chunkU, chunkV, suc, svc);
    hipLaunchKernelGGL(k5_scan,      dim3(1),   dim3(192), 0, stream,
                       chunkU, chunkV, suc, svc, Usuf, Vpref, susuf, svpref);
    hipLaunchKernelGGL(k6_out,       dim3(NV / 4), dim3(256), 0, stream,
                       Wh, s1, sortedIdx, sortedU, sortedV, kcut,
                       Usuf, Vpref, susuf, svpref, out);
}

// Round 2
// 117.891 us; speedup vs baseline: 1.1367x; 1.1367x over previous
//
#include <hip/hip_runtime.h>

// GAT layer, N=8192, IN_F=512, OUT_F=64, alpha=0.2
// exp(lrelu(s1_i+s2_j)) factors on each side of s2_j <= -s1_i:
//   softmax row i = [A_i * suffix(exp(s2)*Wh) + B_i * prefix(exp(.2 s2)*Wh)] / (scalar same)
// over s2 sorted ascending; cut point via binary search. O(N*F) total.

constexpr int NV   = 8192;
constexpr int FIN  = 512;
constexpr int FOUT = 64;
constexpr int CH   = 16;    // sorted positions per chunk
constexpr int NCH  = 512;   // NV / CH

__device__ __forceinline__ unsigned f2key(float x) {
    unsigned b = __float_as_uint(x);
    return (b & 0x80000000u) ? ~b : (b | 0x80000000u);  // order-preserving
}
__device__ __forceinline__ float key2f(unsigned k) {
    unsigned b = (k & 0x80000000u) ? (k ^ 0x80000000u) : ~k;
    return __uint_as_float(b);
}

// ---------------------------------------------------------------- K0
// Wtt[(k>>2)*256 + f*4 + (k&3)] = W[f][k]  (wave-coalesced for K1)
__global__ __launch_bounds__(256) void k0_transpose(const float* __restrict__ W,
                                                    float* __restrict__ Wtt) {
    int id = blockIdx.x * 256 + threadIdx.x;      // 0..32767
    int f = id >> 9;
    int k = id & 511;
    Wtt[(k >> 2) * 256 + f * 4 + (k & 3)] = W[id];
}

// ---------------------------------------------------------------- K1
// Wh = h @ W^T ; s1 = Wh@a1 ; s2 = Wh@a2. Wave owns 8 rows, lane = feature.
__global__ __launch_bounds__(256) void k1_wh(const float* __restrict__ h,
                                             const float* __restrict__ Wtt,
                                             const float* __restrict__ a,
                                             float* __restrict__ Wh,
                                             float* __restrict__ s1,
                                             float* __restrict__ s2) {
    const int lane = threadIdx.x & 63;
    // readfirstlane -> row base provably wave-uniform -> scalar h loads
    const int r0 = __builtin_amdgcn_readfirstlane((blockIdx.x * 4 + (threadIdx.x >> 6)) * 8);
    float acc[8] = {0.f,0.f,0.f,0.f,0.f,0.f,0.f,0.f};
    const float* hbase = h + (size_t)r0 * FIN;
    for (int k4 = 0; k4 < FIN / 4; ++k4) {
        const float4 wv = *reinterpret_cast<const float4*>(Wtt + k4 * 256 + lane * 4);
        #pragma unroll
        for (int r = 0; r < 8; ++r) {
            const float4 hv = *reinterpret_cast<const float4*>(hbase + (size_t)r * FIN + k4 * 4);
            acc[r] = fmaf(hv.x, wv.x, acc[r]);
            acc[r] = fmaf(hv.y, wv.y, acc[r]);
            acc[r] = fmaf(hv.z, wv.z, acc[r]);
            acc[r] = fmaf(hv.w, wv.w, acc[r]);
        }
    }
    const float a1 = a[lane];
    const float a2 = a[FOUT + lane];
    #pragma unroll
    for (int r = 0; r < 8; ++r) {
        Wh[(size_t)(r0 + r) * FOUT + lane] = acc[r];
        float p1 = acc[r] * a1;
        float p2 = acc[r] * a2;
        #pragma unroll
        for (int off = 32; off > 0; off >>= 1) {
            p1 += __shfl_xor(p1, off);
            p2 += __shfl_xor(p2, off);
        }
        if (lane == 0) { s1[r0 + r] = p1; s2[r0 + r] = p2; }
    }
}

// ---------------------------------------------------------------- K2
// Rank each j by (key(s2_j), j) via brute-force count; scatter sorted arrays.
// 256 blocks x 256 threads; 8 threads (segments of 1024) per id.
__global__ __launch_bounds__(256) void k2_rank(const float* __restrict__ s2,
                                               int*      __restrict__ sortedIdx,
                                               unsigned* __restrict__ sortedKey,
                                               float*    __restrict__ sortedU,
                                               float*    __restrict__ sortedV) {
    __shared__ unsigned ks[NV];
    for (int q = 0; q < NV / 256; ++q)
        ks[q * 256 + threadIdx.x] = f2key(s2[q * 256 + threadIdx.x]);
    __syncthreads();
    const int idl = threadIdx.x >> 3;      // 0..31
    const int seg = threadIdx.x & 7;       // 0..7
    const int id  = blockIdx.x * 32 + idl; // 0..8191
    const unsigned key = ks[id];
    int cnt = 0;
    const int base = seg * 1024;
    for (int kk = 0; kk < 256; ++kk) {
        const uint4 v = *reinterpret_cast<const uint4*>(&ks[base + kk * 4]);
        const int gj = base + kk * 4;
        cnt += (int)((v.x < key) | ((v.x == key) & ((gj + 0) < id)));
        cnt += (int)((v.y < key) | ((v.y == key) & ((gj + 1) < id)));
        cnt += (int)((v.z < key) | ((v.z == key) & ((gj + 2) < id)));
        cnt += (int)((v.w < key) | ((v.w == key) & ((gj + 3) < id)));
    }
    cnt += __shfl_xor(cnt, 1);
    cnt += __shfl_xor(cnt, 2);
    cnt += __shfl_xor(cnt, 4);
    if (seg == 0) {
        sortedIdx[cnt] = id;
        sortedKey[cnt] = key;
        const float x = key2f(key);
        sortedU[cnt] = __expf(x);
        sortedV[cnt] = __expf(0.2f * x);
    }
}

// ---------------------------------------------------------------- K4
// Per 16-position chunk: vector sums u*Wh, v*Wh + scalar sums. Wave = chunk.
__global__ __launch_bounds__(256) void k4_chunks(const float* __restrict__ Wh,
                                                 const int*   __restrict__ sortedIdx,
                                                 const float* __restrict__ sortedU,
                                                 const float* __restrict__ sortedV,
                                                 float* __restrict__ chunkU,
                                                 float* __restrict__ chunkV,
                                                 float* __restrict__ suc,
                                                 float* __restrict__ svc) {
    const int f = threadIdx.x & 63;
    const int c = __builtin_amdgcn_readfirstlane(blockIdx.x * 4 + (threadIdx.x >> 6));
    float au = 0.f, av = 0.f, su = 0.f, sv = 0.f;
    #pragma unroll
    for (int q = 0; q < CH; ++q) {
        const int p = c * CH + q;
        const int j = sortedIdx[p];
        const float u = sortedU[p];
        const float v = sortedV[p];
        const float w = Wh[(size_t)j * FOUT + f];
        au = fmaf(u, w, au);
        av = fmaf(v, w, av);
        su += u; sv += v;
    }
    chunkU[c * FOUT + f] = au;
    chunkV[c * FOUT + f] = av;
    if (f == 0) { suc[c] = su; svc[c] = sv; }
}

// ---------------------------------------------------------------- K5
// block 0: U inclusive suffix + susuf. block 1: V exclusive prefix + svpref.
// 256 threads = 64 features x 4 segments of 128 chunks; two-level scan.
__global__ __launch_bounds__(256) void k5_scan(const float* __restrict__ chunkU,
                                               const float* __restrict__ chunkV,
                                               const float* __restrict__ suc,
                                               const float* __restrict__ svc,
                                               float* __restrict__ Usuf,    // [514][64]
                                               float* __restrict__ Vpref,   // [513][64]
                                               float* __restrict__ susuf,   // [514]
                                               float* __restrict__ svpref)  // [513]
{
    __shared__ float segTot[4][FOUT];
    __shared__ float sst[64];
    const int f   = threadIdx.x & 63;
    const int seg = threadIdx.x >> 6;   // 0..3
    const int c0  = seg * 128;
    if (blockIdx.x == 0) {
        float run = 0.f;
        for (int cc = 127; cc >= 0; cc -= 8) {
            float tmp[8];
            #pragma unroll
            for (int q = 0; q < 8; ++q) tmp[q] = chunkU[(c0 + cc - q) * FOUT + f];
            #pragma unroll
            for (int q = 0; q < 8; ++q) { run += tmp[q]; Usuf[(c0 + cc - q) * FOUT + f] = run; }
        }
        segTot[seg][f] = run;
        if (threadIdx.x < 64) {
            const int t = threadIdx.x;
            float rs = 0.f;
            for (int c = t * 8 + 7; c >= t * 8; --c) { rs += suc[c]; susuf[c] = rs; }
            sst[t] = rs;
        }
        __syncthreads();
        float off = 0.f;
        #pragma unroll
        for (int s = 0; s < 4; ++s) if (s > seg) off += segTot[s][f];
        if (seg != 3) {
            #pragma unroll 8
            for (int cc = 0; cc < 128; ++cc) Usuf[(c0 + cc) * FOUT + f] += off;
        }
        if (threadIdx.x < 64) {
            const int t = threadIdx.x;
            float offs = 0.f;
            for (int s = t + 1; s < 64; ++s) offs += sst[s];
            for (int c = t * 8; c < t * 8 + 8; ++c) susuf[c] += offs;
            Usuf[512 * FOUT + t] = 0.f;
            Usuf[513 * FOUT + t] = 0.f;
        }
        if (threadIdx.x == 0) { susuf[512] = 0.f; susuf[513] = 0.f; }
    } else {
        float run = 0.f;
        for (int cc = 0; cc < 128; cc += 8) {
            float tmp[8];
            #pragma unroll
            for (int q = 0; q < 8; ++q) tmp[q] = chunkV[(c0 + cc + q) * FOUT + f];
            #pragma unroll
            for (int q = 0; q < 8; ++q) { Vpref[(c0 + cc + q) * FOUT + f] = run; run += tmp[q]; }
        }
        segTot[seg][f] = run;
        if (threadIdx.x < 64) {
            const int t = threadIdx.x;
            float rs = 0.f;
            for (int c = t * 8; c < t * 8 + 8; ++c) { svpref[c] = rs; rs += svc[c]; }
            sst[t] = rs;
        }
        __syncthreads();
        float off = 0.f;
        #pragma unroll
        for (int s = 0; s < 4; ++s) if (s < seg) off += segTot[s][f];
        if (seg != 0) {
            #pragma unroll 8
            for (int cc = 0; cc < 128; ++cc) Vpref[(c0 + cc) * FOUT + f] += off;
        } else {
            Vpref[512 * FOUT + f] = segTot[0][f] + segTot[1][f] + segTot[2][f] + segTot[3][f];
        }
        if (threadIdx.x < 64) {
            const int t = threadIdx.x;
            float offs = 0.f;
            for (int s = 0; s < t; ++s) offs += sst[s];
            for (int c = t * 8; c < t * 8 + 8; ++c) svpref[c] += offs;
        }
        if (threadIdx.x == 0) {
            float tot = 0.f;
            for (int s = 0; s < 64; ++s) tot += sst[s];
            svpref[512] = tot;
        }
    }
}

// ---------------------------------------------------------------- K6
// Row i: binary-search cut k, combine scans + <=16-gather partial chunk.
__global__ __launch_bounds__(256) void k6_out(const float* __restrict__ Wh,
                                              const float* __restrict__ s1,
                                              const unsigned* __restrict__ sortedKey,
                                              const int*   __restrict__ sortedIdx,
                                              const float* __restrict__ sortedU,
                                              const float* __restrict__ sortedV,
                                              const float* __restrict__ Usuf,
                                              const float* __restrict__ Vpref,
                                              const float* __restrict__ susuf,
                                              const float* __restrict__ svpref,
                                              float* __restrict__ out) {
    const int f = threadIdx.x & 63;
    const int i = __builtin_amdgcn_readfirstlane(blockIdx.x * 4 + (threadIdx.x >> 6));
    const float sv1 = s1[i];
    const unsigned thr = f2key(-sv1);
    int k = 0;                       // = #{p : sortedKey[p] <= thr}
    #pragma unroll
    for (int s = NV; s > 0; s >>= 1) {
        const int nk = k + s;
        if (nk <= NV && sortedKey[nk - 1] <= thr) k = nk;
    }
    const int c = k >> 4;            // CH=16; c in [0,512]
    float accU = 0.f, accV = 0.f, sau = 0.f, sav = 0.f;
    const int pstart = c * CH;
    const int pend = min(pstart + CH, NV);
    for (int p = pstart; p < pend; ++p) {
        const int j = sortedIdx[p];
        const float w = Wh[(size_t)j * FOUT + f];
        if (p < k) {                 // wave-uniform branch
            const float v = sortedV[p];
            accV = fmaf(v, w, accV);
            sav += v;
        } else {
            const float u = sortedU[p];
            accU = fmaf(u, w, accU);
            sau += u;
        }
    }
    const int cn = c + 1;            // <=513
    const float A = __expf(sv1);
    const float B = __expf(0.2f * sv1);
    const float numer = A * (Usuf[cn * FOUT + f] + accU) + B * (Vpref[c * FOUT + f] + accV);
    const float den   = A * (susuf[cn] + sau)            + B * (svpref[c] + sav);
    out[(size_t)i * FOUT + f] = numer / den;
}

// ----------------------------------------------------------------
extern "C" void kernel_launch(void* const* d_in, const int* in_sizes, int n_in,
                              void* d_out, int out_size, void* d_ws, size_t ws_size,
                              hipStream_t stream) {
    (void)in_sizes; (void)n_in; (void)out_size; (void)ws_size;
    const float* h = (const float*)d_in[0];
    // d_in[1] = adj : unused by the reference computation
    const float* W = (const float*)d_in[2];
    const float* a = (const float*)d_in[3];
    float* out = (float*)d_out;

    int*      sortedIdx = (int*)d_ws;               // 8192
    unsigned* sortedKey = (unsigned*)d_ws + NV;     // 8192
    float* fws = (float*)d_ws + 2 * NV;
    float* Wtt     = fws;  fws += 32768;            // 512*64
    float* Wh      = fws;  fws += (size_t)NV * FOUT;
    float* s1      = fws;  fws += NV;
    float* s2      = fws;  fws += NV;
    float* sortedU = fws;  fws += NV;
    float* sortedV = fws;  fws += NV;
    float* chunkU  = fws;  fws += NCH * FOUT;
    float* chunkV  = fws;  fws += NCH * FOUT;
    float* suc     = fws;  fws += NCH;
    float* svc     = fws;  fws += NCH;
    float* Usuf    = fws;  fws += 514 * FOUT;
    float* Vpref   = fws;  fws += 513 * FOUT;
    float* susuf   = fws;  fws += 514;
    float* svpref  = fws;  fws += 513;

    hipLaunchKernelGGL(k0_transpose, dim3(128),    dim3(256), 0, stream, W, Wtt);
    hipLaunchKernelGGL(k1_wh,        dim3(256),    dim3(256), 0, stream, h, Wtt, a, Wh, s1, s2);
    hipLaunchKernelGGL(k2_rank,      dim3(256),    dim3(256), 0, stream,
                       s2, sortedIdx, sortedKey, sortedU, sortedV);
    hipLaunchKernelGGL(k4_chunks,    dim3(NCH/4),  dim3(256), 0, stream,
                       Wh, sortedIdx, sortedU, sortedV, chunkU, chunkV, suc, svc);
    hipLaunchKernelGGL(k5_scan,      dim3(2),      dim3(256), 0, stream,
                       chunkU, chunkV, suc, svc, Usuf, Vpref, susuf, svpref);
    hipLaunchKernelGGL(k6_out,       dim3(NV/4),   dim3(256), 0, stream,
                       Wh, s1, sortedKey, sortedIdx, sortedU, sortedV,
                       Usuf, Vpref, susuf, svpref, out);
}